// Round 4
// baseline (454.271 us; speedup 1.0000x reference)
//
#include <hip/hip_runtime.h>
#include <hip/hip_bf16.h>

#define BB  16384
#define F   40
#define WPB 4    // waves (= independent batches) per workgroup

typedef __bf16 bf16;
typedef __bf16 bf16x8 __attribute__((ext_vector_type(8)));
typedef __bf16 bf16x4 __attribute__((ext_vector_type(4)));
typedef short  s16x4  __attribute__((ext_vector_type(4)));
typedef float  f32x4  __attribute__((ext_vector_type(4)));

// MFMA 16x16x32 bf16 layouts:
//   A-frag: lane holds A[m = lane&15][k = (lane>>4)*8 + j]   (8 consec k)
//   B-frag: lane holds B[k = (lane>>4)*8 + j][n = lane&15]
//   C/D   : lane holds C[row = (lane>>4)*4 + r][col = lane&15]
// MFMA 16x16x16 bf16 layouts (gfx950 keeps the gfx90a _1k shape):
//   A-frag: lane holds A[m = lane&15][k = (lane>>4)*4 + j]   (4 consec k)
//   B-frag: lane holds B[k = (lane>>4)*4 + j][n = lane&15]
// KEY: a 16x16 C-output bf16x4 (4 consec rows @ col=l16) IS, bit-for-bit,
//   - the B-frag of that tile's matrix (k = the 4-consec-row axis), and
//   - the A-frag of its transpose.
// So chaining products through mfma16 needs NO LDS round trip at all.

__device__ __forceinline__ bf16x8 cvt8(float4 a, float4 b) {
    bf16x8 f;
    f[0] = (bf16)a.x; f[1] = (bf16)a.y; f[2] = (bf16)a.z; f[3] = (bf16)a.w;
    f[4] = (bf16)b.x; f[5] = (bf16)b.y; f[6] = (bf16)b.z; f[7] = (bf16)b.w;
    return f;
}
__device__ __forceinline__ bf16x4 cvt4(float4 a) {
    bf16x4 f;
    f[0] = (bf16)a.x; f[1] = (bf16)a.y; f[2] = (bf16)a.z; f[3] = (bf16)a.w;
    return f;
}
__device__ __forceinline__ bf16x4 pack4(f32x4 a) {
    bf16x4 f;
    f[0] = (bf16)a[0]; f[1] = (bf16)a[1]; f[2] = (bf16)a[2]; f[3] = (bf16)a[3];
    return f;
}
__device__ __forceinline__ f32x4 mfma32(bf16x8 a, bf16x8 b, f32x4 c) {
    return __builtin_amdgcn_mfma_f32_16x16x32_bf16(a, b, c, 0, 0, 0);
}
__device__ __forceinline__ f32x4 mfma16(bf16x4 a, bf16x4 b, f32x4 c) {
#if __has_builtin(__builtin_amdgcn_mfma_f32_16x16x16_bf16)
    return __builtin_amdgcn_mfma_f32_16x16x16_bf16(a, b, c, 0, 0, 0);
#else
    // gfx90a-lineage builtin, V4fV4sV4sV4f signature; instruction exists on gfx950
    return __builtin_amdgcn_mfma_f32_16x16x16bf16_1k(
        __builtin_bit_cast(s16x4, a), __builtin_bit_cast(s16x4, b), c, 0, 0, 0);
#endif
}

// ---- prep: block0 computes G = Wq*Wk^T via MFMA and packs it; blocks 1,2 pack Wv/Wr ----
__global__ __launch_bounds__(256)
void prep_weights(const float* __restrict__ Wq, const float* __restrict__ Wk,
                  const float* __restrict__ Wv, const float* __restrict__ Wr,
                  bf16* __restrict__ ws)
{
    const int tid = threadIdx.x;
    if (blockIdx.x > 0) {
        const float* W = (blockIdx.x == 1) ? Wv : Wr;
        bf16* dst = ws + 4096 * blockIdx.x;
        for (int f = tid; f < 4096; f += 256) {
            int j = f & 7, ln = (f >> 3) & 63, kt = (f >> 9) & 1, nt = f >> 10;
            dst[f] = (bf16)W[(kt * 32 + (ln >> 4) * 8 + j) * 64 + nt * 16 + (ln & 15)];
        }
        return;
    }
    __shared__ float Gs[64 * 64];
    if (tid < 64) {   // one wave: G[d][d'] = sum_e Wq[d][e] * Wk[d'][e]
        const int l16 = tid & 15, quad = tid >> 4;
        bf16x8 aq[4][2], ak[4][2];
        #pragma unroll
        for (int mt = 0; mt < 4; ++mt)
            #pragma unroll
            for (int kt = 0; kt < 2; ++kt) {
                const float* pq = Wq + (mt * 16 + l16) * 64 + kt * 32 + quad * 8;
                const float* pk = Wk + (mt * 16 + l16) * 64 + kt * 32 + quad * 8;
                aq[mt][kt] = cvt8(*(const float4*)pq, *(const float4*)(pq + 4));
                ak[mt][kt] = cvt8(*(const float4*)pk, *(const float4*)(pk + 4));
            }
        #pragma unroll
        for (int mt = 0; mt < 4; ++mt)
            #pragma unroll
            for (int nt = 0; nt < 4; ++nt) {
                f32x4 acc = {0.f, 0.f, 0.f, 0.f};
                acc = mfma32(aq[mt][0], ak[nt][0], acc);
                acc = mfma32(aq[mt][1], ak[nt][1], acc);
                #pragma unroll
                for (int r = 0; r < 4; ++r)
                    Gs[(mt * 16 + quad * 4 + r) * 64 + nt * 16 + l16] = acc[r];
            }
    }
    __syncthreads();
    for (int f = tid; f < 4096; f += 256) {
        int j = f & 7, ln = (f >> 3) & 63, kt = (f >> 9) & 1, nt = f >> 10;
        ws[f] = (bf16)Gs[(kt * 32 + (ln >> 4) * 8 + j) * 64 + nt * 16 + (ln & 15)];
    }
}

// ---- main: 4 waves/block, 1 batch/wave, ZERO LDS, no barriers ----
// 1-wave workgroups capped at the ~16 WG/CU slot limit (43% occupancy measured);
// 4-wave blocks make occupancy VGPR-limited. min 6 waves/EU -> VGPR cap 84
// (R2 measured 60; headroom so the allocator never spills to meet the bound).
__global__ __launch_bounds__(64 * WPB, 6)
void attn_fused(const float* __restrict__ X, const bf16* __restrict__ wfrag,
                float* __restrict__ Out)
{
    const int lane = threadIdx.x & 63;
    const int wav  = threadIdx.x >> 6;
    const int l16  = lane & 15;
    const int quad = lane >> 4;
    const size_t b = (size_t)blockIdx.x * WPB + wav;
    const float* Xb = X + b * (F * 64);

    int rowm[3];
    #pragma unroll
    for (int mt = 0; mt < 3; ++mt) {
        int r = mt * 16 + l16; rowm[mt] = (r >= F) ? (F - 1) : r;  // finite pad rows
    }

    // ---- X K=32 A/B-frags (q', v, O-residual phases) ----
    bf16x8 xf[3][2];
    #pragma unroll
    for (int mt = 0; mt < 3; ++mt)
        #pragma unroll
        for (int kt = 0; kt < 2; ++kt) {
            const float* p = Xb + rowm[mt] * 64 + kt * 32 + quad * 8;
            xf[mt][kt] = cvt8(*(const float4*)p, *(const float4*)(p + 4));
        }

    // ---- X K=16 A-frags (S phase): lane holds X[row=16mt+l16][e=16kt+4*quad+j] ----
    bf16x4 xa[3][4];
    #pragma unroll
    for (int mt = 0; mt < 3; ++mt)
        #pragma unroll
        for (int kt = 0; kt < 4; ++kt) {
            const float* p = Xb + rowm[mt] * 64 + kt * 16 + quad * 4;
            xa[mt][kt] = cvt4(*(const float4*)p);
        }

    const bf16x8* gF = (const bf16x8*)wfrag;   // B-frags of G  == A-frags of G^T
    const bf16x8* vF = gF + 512;               // B-frags of Wv
    const bf16x8* rF = gF + 1024;              // B-frags of Wr == A-frags of Wr^T

    // ---- q'^T = G^T @ X^T : lane = q'[m=16nt+l16][e=16mt+4*quad+r] -> pkQ bf16x4 ----
    bf16x4 pkQ[4][3];
    #pragma unroll
    for (int mt = 0; mt < 4; ++mt) {           // e-tiles
        bf16x8 a0 = gF[(mt * 2 + 0) * 64 + lane];
        bf16x8 a1 = gF[(mt * 2 + 1) * 64 + lane];
        #pragma unroll
        for (int nt = 0; nt < 3; ++nt) {       // m-tiles
            f32x4 acc = {0.f, 0.f, 0.f, 0.f};
            acc = mfma32(a0, xf[nt][0], acc);
            acc = mfma32(a1, xf[nt][1], acc);
            pkQ[mt][nt] = pack4(acc);
        }
    }

    // ---- S^T = X @ q'^T via mfma16: pkQ[kt][nt] IS the B-frag (q'^T), no LDS ----
    f32x4 sacc[3][3];   // [mt_k'][nt_m]
    #pragma unroll
    for (int mt = 0; mt < 3; ++mt)
        #pragma unroll
        for (int nt = 0; nt < 3; ++nt) {
            f32x4 acc = {0.f, 0.f, 0.f, 0.f};
            #pragma unroll
            for (int kt = 0; kt < 4; ++kt)
                acc = mfma16(xa[mt][kt], pkQ[kt][nt], acc);
            sacc[mt][nt] = acc;
        }

    // ---- softmax over k' (rows of S^T): in-lane 12 values + 2 shfls -> pkP regs ----
    // lane holds S^T[k' = 16mt+4*quad+r][m = 16nt+l16]; k' >= 40 <=> mt==2 && quad>=2.
    // No max pass: |s| small (q'=XG, std ~1.3), exp fp32-safe (validated R2/R3).
    const bool dead = (quad >= 2);
    bf16x4 pkP[3][3];   // P^T tiles, directly the PV B-frags
    #pragma unroll
    for (int nt = 0; nt < 3; ++nt) {
        float ex[3][4]; float sum = 0.f;
        #pragma unroll
        for (int mt = 0; mt < 3; ++mt)
            #pragma unroll
            for (int r = 0; r < 4; ++r) {
                float e = (mt == 2 && dead) ? 0.f : __expf(sacc[mt][nt][r]);
                ex[mt][r] = e; sum += e;
            }
        sum += __shfl_xor(sum, 16, 64);
        sum += __shfl_xor(sum, 32, 64);
        float inv = 1.0f / sum;
        #pragma unroll
        for (int mt = 0; mt < 3; ++mt) {
            bf16x4 pk;
            pk[0] = (bf16)(ex[mt][0] * inv); pk[1] = (bf16)(ex[mt][1] * inv);
            pk[2] = (bf16)(ex[mt][2] * inv); pk[3] = (bf16)(ex[mt][3] * inv);
            pkP[mt][nt] = pk;
        }
    }

    // ---- v = X @ Wv : lane = v[k'=16mt+4*quad+r][e=16nt+l16] -> pkV (A-frags of V^T) ----
    // (after softmax so pkV isn't live across the S-phase register peak)
    bf16x4 pkV[3][4];
    #pragma unroll
    for (int nt = 0; nt < 4; ++nt) {           // e-tiles
        bf16x8 b0 = vF[(nt * 2 + 0) * 64 + lane];
        bf16x8 b1 = vF[(nt * 2 + 1) * 64 + lane];
        #pragma unroll
        for (int mt = 0; mt < 3; ++mt) {       // k'-tiles
            f32x4 acc = {0.f, 0.f, 0.f, 0.f};
            acc = mfma32(xf[mt][0], b0, acc);
            acc = mfma32(xf[mt][1], b1, acc);
            pkV[mt][nt] = pack4(acc);
        }
    }

    // ---- O^T = Wr^T@X^T + V^T@P^T, two e-halves (caps oacc at 24 VGPR) ----
    // PV k'-range is 0..47 only: k' 40..47 = finite clamp-dup v rows * exact-zero P.
    float* Ob = Out + b * (F * 64);
    #pragma unroll
    for (int half = 0; half < 2; ++half) {
        f32x4 oacc[2][3];
        #pragma unroll
        for (int me = 0; me < 2; ++me) {       // e-tiles within half
            int mt = half * 2 + me;
            bf16x8 a0 = rF[(mt * 2 + 0) * 64 + lane];
            bf16x8 a1 = rF[(mt * 2 + 1) * 64 + lane];
            #pragma unroll
            for (int nt = 0; nt < 3; ++nt) {
                f32x4 acc = {0.f, 0.f, 0.f, 0.f};
                acc = mfma32(a0, xf[nt][0], acc);
                acc = mfma32(a1, xf[nt][1], acc);
                oacc[me][nt] = acc;
            }
        }
        #pragma unroll
        for (int me = 0; me < 2; ++me) {
            int mt = half * 2 + me;
            #pragma unroll
            for (int nt = 0; nt < 3; ++nt) {
                f32x4 acc = oacc[me][nt];
                #pragma unroll
                for (int kt = 0; kt < 3; ++kt)
                    acc = mfma16(pkV[kt][mt], pkP[kt][nt], acc);
                oacc[me][nt] = acc;
            }
        }
        // store: per row, the two 64 B chunks of this 128 B half back-to-back
        #pragma unroll
        for (int nt = 0; nt < 3; ++nt) {
            int m = nt * 16 + l16;
            if (m < F) {
                #pragma unroll
                for (int me = 0; me < 2; ++me) {
                    f32x4 st;
                    st[0] = fmaxf(oacc[me][nt][0], 0.f); st[1] = fmaxf(oacc[me][nt][1], 0.f);
                    st[2] = fmaxf(oacc[me][nt][2], 0.f); st[3] = fmaxf(oacc[me][nt][3], 0.f);
                    // nontemporal: output is write-once; keep X resident in L2/L3.
                    __builtin_nontemporal_store(st,
                        (f32x4*)&Ob[m * 64 + (half * 2 + me) * 16 + quad * 4]);
                }
            }
        }
    }
}

extern "C" void kernel_launch(void* const* d_in, const int* in_sizes, int n_in,
                              void* d_out, int out_size, void* d_ws, size_t ws_size,
                              hipStream_t stream) {
    const float* X  = (const float*)d_in[0];
    const float* Wq = (const float*)d_in[1];
    const float* Wk = (const float*)d_in[2];
    const float* Wv = (const float*)d_in[3];
    const float* Wr = (const float*)d_in[4];
    float* Out = (float*)d_out;
    bf16* ws = (bf16*)d_ws;   // 12288 bf16 fragment-packed G/Wv/Wr

    prep_weights<<<3, 256, 0, stream>>>(Wq, Wk, Wv, Wr, ws);
    attn_fused<<<BB / WPB, 64 * WPB, 0, stream>>>(X, ws, Out);
}

// Round 5
// 333.045 us; speedup vs baseline: 1.3640x; 1.3640x over previous
//
#include <hip/hip_runtime.h>
#include <hip/hip_bf16.h>

#define BB  16384
#define F   40
#define WPB 4    // waves (= independent batches) per workgroup

typedef __bf16 bf16;
typedef __bf16 bf16x8 __attribute__((ext_vector_type(8)));
typedef __bf16 bf16x4 __attribute__((ext_vector_type(4)));
typedef short  s16x4  __attribute__((ext_vector_type(4)));
typedef float  f32x4  __attribute__((ext_vector_type(4)));

// MFMA 16x16x32 bf16 layouts:
//   A-frag: lane holds A[m = lane&15][k = (lane>>4)*8 + j]   (8 consec k)
//   B-frag: lane holds B[k = (lane>>4)*8 + j][n = lane&15]
//   C/D   : lane holds C[row = (lane>>4)*4 + r][col = lane&15]
// MFMA 16x16x16 bf16 layouts (gfx950 keeps the gfx90a _1k shape):
//   A-frag: lane holds A[m = lane&15][k = (lane>>4)*4 + j]   (4 consec k)
//   B-frag: lane holds B[k = (lane>>4)*4 + j][n = lane&15]
// KEY: a 16x16 C-output bf16x4 (4 consec rows @ col=l16) IS, bit-for-bit,
//   - the B-frag of that tile's matrix (k = the 4-consec-row axis), and
//   - the A-frag of its transpose.
// So chaining products through mfma16 needs NO LDS round trip at all.

__device__ __forceinline__ bf16x8 cvt8(float4 a, float4 b) {
    bf16x8 f;
    f[0] = (bf16)a.x; f[1] = (bf16)a.y; f[2] = (bf16)a.z; f[3] = (bf16)a.w;
    f[4] = (bf16)b.x; f[5] = (bf16)b.y; f[6] = (bf16)b.z; f[7] = (bf16)b.w;
    return f;
}
__device__ __forceinline__ bf16x4 cvt4(float4 a) {
    bf16x4 f;
    f[0] = (bf16)a.x; f[1] = (bf16)a.y; f[2] = (bf16)a.z; f[3] = (bf16)a.w;
    return f;
}
__device__ __forceinline__ bf16x4 pack4(f32x4 a) {
    bf16x4 f;
    f[0] = (bf16)a[0]; f[1] = (bf16)a[1]; f[2] = (bf16)a[2]; f[3] = (bf16)a[3];
    return f;
}
__device__ __forceinline__ f32x4 mfma32(bf16x8 a, bf16x8 b, f32x4 c) {
    return __builtin_amdgcn_mfma_f32_16x16x32_bf16(a, b, c, 0, 0, 0);
}
__device__ __forceinline__ f32x4 mfma16(bf16x4 a, bf16x4 b, f32x4 c) {
#if __has_builtin(__builtin_amdgcn_mfma_f32_16x16x16_bf16)
    return __builtin_amdgcn_mfma_f32_16x16x16_bf16(a, b, c, 0, 0, 0);
#else
    // gfx90a-lineage builtin, V4fV4sV4sV4f signature; instruction exists on gfx950
    return __builtin_amdgcn_mfma_f32_16x16x16bf16_1k(
        __builtin_bit_cast(s16x4, a), __builtin_bit_cast(s16x4, b), c, 0, 0, 0);
#endif
}

// ---- prep: block0 computes G = Wq*Wk^T via MFMA and packs it; blocks 1,2 pack Wv/Wr ----
__global__ __launch_bounds__(256)
void prep_weights(const float* __restrict__ Wq, const float* __restrict__ Wk,
                  const float* __restrict__ Wv, const float* __restrict__ Wr,
                  bf16* __restrict__ ws)
{
    const int tid = threadIdx.x;
    if (blockIdx.x > 0) {
        const float* W = (blockIdx.x == 1) ? Wv : Wr;
        bf16* dst = ws + 4096 * blockIdx.x;
        for (int f = tid; f < 4096; f += 256) {
            int j = f & 7, ln = (f >> 3) & 63, kt = (f >> 9) & 1, nt = f >> 10;
            dst[f] = (bf16)W[(kt * 32 + (ln >> 4) * 8 + j) * 64 + nt * 16 + (ln & 15)];
        }
        return;
    }
    __shared__ float Gs[64 * 64];
    if (tid < 64) {   // one wave: G[d][d'] = sum_e Wq[d][e] * Wk[d'][e]
        const int l16 = tid & 15, quad = tid >> 4;
        bf16x8 aq[4][2], ak[4][2];
        #pragma unroll
        for (int mt = 0; mt < 4; ++mt)
            #pragma unroll
            for (int kt = 0; kt < 2; ++kt) {
                const float* pq = Wq + (mt * 16 + l16) * 64 + kt * 32 + quad * 8;
                const float* pk = Wk + (mt * 16 + l16) * 64 + kt * 32 + quad * 8;
                aq[mt][kt] = cvt8(*(const float4*)pq, *(const float4*)(pq + 4));
                ak[mt][kt] = cvt8(*(const float4*)pk, *(const float4*)(pk + 4));
            }
        #pragma unroll
        for (int mt = 0; mt < 4; ++mt)
            #pragma unroll
            for (int nt = 0; nt < 4; ++nt) {
                f32x4 acc = {0.f, 0.f, 0.f, 0.f};
                acc = mfma32(aq[mt][0], ak[nt][0], acc);
                acc = mfma32(aq[mt][1], ak[nt][1], acc);
                #pragma unroll
                for (int r = 0; r < 4; ++r)
                    Gs[(mt * 16 + quad * 4 + r) * 64 + nt * 16 + l16] = acc[r];
            }
    }
    __syncthreads();
    for (int f = tid; f < 4096; f += 256) {
        int j = f & 7, ln = (f >> 3) & 63, kt = (f >> 9) & 1, nt = f >> 10;
        ws[f] = (bf16)Gs[(kt * 32 + (ln >> 4) * 8 + j) * 64 + nt * 16 + (ln & 15)];
    }
}

// ---- main: 4 waves/block, 1 batch/wave, ZERO LDS, no barriers ----
// R2: 1-wave WGs capped at ~16 WG/CU slot limit (43% occ). R4: 4-wave WGs lifted
// occ to 56% BUT min_waves=6 clamped VGPR to 40 -> ~20 regs/lane spilled to
// scratch -> +520 MB HBM traffic -> 256 us. Fix: min_waves=4 (VGPR cap 128,
// non-binding for the ~60 this code needs) -> no spill, occupancy VGPR-limited.
__global__ __launch_bounds__(64 * WPB, 4)
void attn_fused(const float* __restrict__ X, const bf16* __restrict__ wfrag,
                float* __restrict__ Out)
{
    const int lane = threadIdx.x & 63;
    const int wav  = threadIdx.x >> 6;
    const int l16  = lane & 15;
    const int quad = lane >> 4;
    const size_t b = (size_t)blockIdx.x * WPB + wav;
    const float* Xb = X + b * (F * 64);

    int rowm[3];
    #pragma unroll
    for (int mt = 0; mt < 3; ++mt) {
        int r = mt * 16 + l16; rowm[mt] = (r >= F) ? (F - 1) : r;  // finite pad rows
    }

    // ---- X K=32 A/B-frags (q', v, O-residual phases) ----
    bf16x8 xf[3][2];
    #pragma unroll
    for (int mt = 0; mt < 3; ++mt)
        #pragma unroll
        for (int kt = 0; kt < 2; ++kt) {
            const float* p = Xb + rowm[mt] * 64 + kt * 32 + quad * 8;
            xf[mt][kt] = cvt8(*(const float4*)p, *(const float4*)(p + 4));
        }

    // ---- X K=16 A-frags (S phase): lane holds X[row=16mt+l16][e=16kt+4*quad+j] ----
    bf16x4 xa[3][4];
    #pragma unroll
    for (int mt = 0; mt < 3; ++mt)
        #pragma unroll
        for (int kt = 0; kt < 4; ++kt) {
            const float* p = Xb + rowm[mt] * 64 + kt * 16 + quad * 4;
            xa[mt][kt] = cvt4(*(const float4*)p);
        }

    const bf16x8* gF = (const bf16x8*)wfrag;   // B-frags of G  == A-frags of G^T
    const bf16x8* vF = gF + 512;               // B-frags of Wv
    const bf16x8* rF = gF + 1024;              // B-frags of Wr == A-frags of Wr^T

    // ---- q'^T = G^T @ X^T : lane = q'[m=16nt+l16][e=16mt+4*quad+r] -> pkQ bf16x4 ----
    bf16x4 pkQ[4][3];
    #pragma unroll
    for (int mt = 0; mt < 4; ++mt) {           // e-tiles
        bf16x8 a0 = gF[(mt * 2 + 0) * 64 + lane];
        bf16x8 a1 = gF[(mt * 2 + 1) * 64 + lane];
        #pragma unroll
        for (int nt = 0; nt < 3; ++nt) {       // m-tiles
            f32x4 acc = {0.f, 0.f, 0.f, 0.f};
            acc = mfma32(a0, xf[nt][0], acc);
            acc = mfma32(a1, xf[nt][1], acc);
            pkQ[mt][nt] = pack4(acc);
        }
    }

    // ---- S^T = X @ q'^T via mfma16: pkQ[kt][nt] IS the B-frag (q'^T), no LDS ----
    f32x4 sacc[3][3];   // [mt_k'][nt_m]
    #pragma unroll
    for (int mt = 0; mt < 3; ++mt)
        #pragma unroll
        for (int nt = 0; nt < 3; ++nt) {
            f32x4 acc = {0.f, 0.f, 0.f, 0.f};
            #pragma unroll
            for (int kt = 0; kt < 4; ++kt)
                acc = mfma16(xa[mt][kt], pkQ[kt][nt], acc);
            sacc[mt][nt] = acc;
        }

    // ---- softmax over k' (rows of S^T): in-lane 12 values + 2 shfls -> pkP regs ----
    // lane holds S^T[k' = 16mt+4*quad+r][m = 16nt+l16]; k' >= 40 <=> mt==2 && quad>=2.
    // No max pass: |s| small (q'=XG, std ~1.3), exp fp32-safe (validated R2/R3).
    const bool dead = (quad >= 2);
    bf16x4 pkP[3][3];   // P^T tiles, directly the PV B-frags
    #pragma unroll
    for (int nt = 0; nt < 3; ++nt) {
        float ex[3][4]; float sum = 0.f;
        #pragma unroll
        for (int mt = 0; mt < 3; ++mt)
            #pragma unroll
            for (int r = 0; r < 4; ++r) {
                float e = (mt == 2 && dead) ? 0.f : __expf(sacc[mt][nt][r]);
                ex[mt][r] = e; sum += e;
            }
        sum += __shfl_xor(sum, 16, 64);
        sum += __shfl_xor(sum, 32, 64);
        float inv = 1.0f / sum;
        #pragma unroll
        for (int mt = 0; mt < 3; ++mt) {
            bf16x4 pk;
            pk[0] = (bf16)(ex[mt][0] * inv); pk[1] = (bf16)(ex[mt][1] * inv);
            pk[2] = (bf16)(ex[mt][2] * inv); pk[3] = (bf16)(ex[mt][3] * inv);
            pkP[mt][nt] = pk;
        }
    }

    // ---- v = X @ Wv : lane = v[k'=16mt+4*quad+r][e=16nt+l16] -> pkV (A-frags of V^T) ----
    // (after softmax so pkV isn't live across the S-phase register peak)
    bf16x4 pkV[3][4];
    #pragma unroll
    for (int nt = 0; nt < 4; ++nt) {           // e-tiles
        bf16x8 b0 = vF[(nt * 2 + 0) * 64 + lane];
        bf16x8 b1 = vF[(nt * 2 + 1) * 64 + lane];
        #pragma unroll
        for (int mt = 0; mt < 3; ++mt) {       // k'-tiles
            f32x4 acc = {0.f, 0.f, 0.f, 0.f};
            acc = mfma32(xf[mt][0], b0, acc);
            acc = mfma32(xf[mt][1], b1, acc);
            pkV[mt][nt] = pack4(acc);
        }
    }

    // ---- O^T = Wr^T@X^T + V^T@P^T, two e-halves (caps oacc at 24 VGPR) ----
    // PV k'-range is 0..47 only: k' 40..47 = finite clamp-dup v rows * exact-zero P.
    float* Ob = Out + b * (F * 64);
    #pragma unroll
    for (int half = 0; half < 2; ++half) {
        f32x4 oacc[2][3];
        #pragma unroll
        for (int me = 0; me < 2; ++me) {       // e-tiles within half
            int mt = half * 2 + me;
            bf16x8 a0 = rF[(mt * 2 + 0) * 64 + lane];
            bf16x8 a1 = rF[(mt * 2 + 1) * 64 + lane];
            #pragma unroll
            for (int nt = 0; nt < 3; ++nt) {
                f32x4 acc = {0.f, 0.f, 0.f, 0.f};
                acc = mfma32(a0, xf[nt][0], acc);
                acc = mfma32(a1, xf[nt][1], acc);
                oacc[me][nt] = acc;
            }
        }
        #pragma unroll
        for (int me = 0; me < 2; ++me) {
            int mt = half * 2 + me;
            #pragma unroll
            for (int nt = 0; nt < 3; ++nt) {
                f32x4 acc = oacc[me][nt];
                #pragma unroll
                for (int kt = 0; kt < 3; ++kt)
                    acc = mfma16(pkV[kt][mt], pkP[kt][nt], acc);
                oacc[me][nt] = acc;
            }
        }
        // store: per row, the two 64 B chunks of this 128 B half back-to-back
        #pragma unroll
        for (int nt = 0; nt < 3; ++nt) {
            int m = nt * 16 + l16;
            if (m < F) {
                #pragma unroll
                for (int me = 0; me < 2; ++me) {
                    f32x4 st;
                    st[0] = fmaxf(oacc[me][nt][0], 0.f); st[1] = fmaxf(oacc[me][nt][1], 0.f);
                    st[2] = fmaxf(oacc[me][nt][2], 0.f); st[3] = fmaxf(oacc[me][nt][3], 0.f);
                    // nontemporal: output is write-once; keep X resident in L2/L3.
                    __builtin_nontemporal_store(st,
                        (f32x4*)&Ob[m * 64 + (half * 2 + me) * 16 + quad * 4]);
                }
            }
        }
    }
}

extern "C" void kernel_launch(void* const* d_in, const int* in_sizes, int n_in,
                              void* d_out, int out_size, void* d_ws, size_t ws_size,
                              hipStream_t stream) {
    const float* X  = (const float*)d_in[0];
    const float* Wq = (const float*)d_in[1];
    const float* Wk = (const float*)d_in[2];
    const float* Wv = (const float*)d_in[3];
    const float* Wr = (const float*)d_in[4];
    float* Out = (float*)d_out;
    bf16* ws = (bf16*)d_ws;   // 12288 bf16 fragment-packed G/Wv/Wr

    prep_weights<<<3, 256, 0, stream>>>(Wq, Wk, Wv, Wr, ws);
    attn_fused<<<BB / WPB, 64 * WPB, 0, stream>>>(X, ws, Out);
}